// Round 19
// baseline (655.214 us; speedup 1.0000x reference)
//
#include <hip/hip_runtime.h>
#include <hip/hip_bf16.h>
#include <math.h>

#define NB 64
#define PP 7

typedef __attribute__((ext_vector_type(8))) short short8;
typedef __attribute__((ext_vector_type(4))) float f32x4;

// round-to-nearest-even bf16 from f32, packed pair -> u32 (lo=a, hi=b)
static __device__ inline unsigned bf16r(float f) {
    unsigned u = __builtin_bit_cast(unsigned, f);
    u += 0x7fffu + ((u >> 16) & 1u);
    return u >> 16;
}
static __device__ inline unsigned pack2(float a, float b) {
    return bf16r(a) | (bf16r(b) << 16);
}
static __device__ inline float bf2f(short s) {
    return __builtin_bit_cast(float, ((unsigned)(unsigned short)s) << 16);
}

// ---------------------------------------------------------------------------
// crop v6 (R17-proven: VGPR 36, occ 71%): masked-fmac direct accumulation.
// ---------------------------------------------------------------------------
template<int H, int VEC, int GRP>
__device__ inline void crop_dev(
    int bx, int n, const float* __restrict__ x, const int* __restrict__ patchs,
    float* __restrict__ out, int C, int num, int den, int ldo, int col0)
{
    constexpr int USED = H / VEC;
    constexpr int PPWAVE = 64 / GRP;
    int tid = threadIdx.x, lane = tid & 63, wv = tid >> 6;
    int sub = lane / GRP, xl = lane & (GRP - 1);
    bool act = xl < USED;
    int c = bx * (4 * PPWAVE) + wv * PPWAVE + sub;

    int y0s[PP], yds[PP], x0s[PP], x1s[PP], zer[PP];
    float rarea[PP];
    #pragma unroll
    for (int p = 0; p < PP; ++p) {
        int p0 = patchs[(n * PP + p) * 4 + 0];
        int p1 = patchs[(n * PP + p) * 4 + 1];
        int p2 = patchs[(n * PP + p) * 4 + 2];
        int p3 = patchs[(n * PP + p) * 4 + 3];
        int y0 = p0 * num / den, y1 = p1 * num / den;
        int xx0 = p2 * num / den, xx1 = p3 * num / den;
        y0s[p] = y0; yds[p] = y1 - y0;
        x0s[p] = xx0; x1s[p] = xx1;
        rarea[p] = 1.f / (float)((y1 - y0 + 1) * (xx1 - xx0 + 1));
        zer[p] = (p0 | p1 | p2 | p3) == 0;
    }

    const float* pl = x + ((size_t)n * C + c) * (H * H) + (act ? xl * VEC : 0);

    float acc[PP][VEC];
    #pragma unroll
    for (int p = 0; p < PP; ++p)
        #pragma unroll
        for (int e = 0; e < VEC; ++e) acc[p][e] = 0.f;

    #pragma unroll 4
    for (int y = 0; y < H; ++y) {
        float v[VEC];
        if constexpr (VEC == 4) {
            float4 t = *reinterpret_cast<const float4*>(pl + y * H);
            v[0] = t.x; v[1] = t.y; v[2] = t.z; v[3] = t.w;
        } else {
            float2 t = *reinterpret_cast<const float2*>(pl + y * H);
            v[0] = t.x; v[1] = t.y;
        }
        #pragma unroll
        for (int p = 0; p < PP; ++p) {
            float m = ((unsigned)(y - y0s[p]) <= (unsigned)yds[p]) ? 1.f : 0.f;
            #pragma unroll
            for (int e = 0; e < VEC; ++e)
                acc[p][e] = fmaf(m, v[e], acc[p][e]);
        }
    }

    #pragma unroll
    for (int p = 0; p < PP; ++p) {
        float d = 0.f;
        #pragma unroll
        for (int e = 0; e < VEC; ++e) {
            int col = xl * VEC + e;
            if (col >= x0s[p] && col <= x1s[p]) d += acc[p][e];
        }
        #pragma unroll
        for (int off = GRP / 2; off >= 1; off >>= 1)
            d += __shfl_xor(d, off, 64);
        if (act && xl == 0)
            out[(size_t)(n * PP + p) * ldo + col0 + c] = zer[p] ? 0.f : d * rarea[p];
    }
}

// f32 -> bf16 cvt device fn, 8 elems/thread
__device__ inline void cvt_dev(
    int b, const float* __restrict__ in, uint4* __restrict__ out, int n8)
{
    int idx = b * 256 + threadIdx.x;
    if (idx >= n8) return;
    const float4* p = reinterpret_cast<const float4*>(in) + 2 * (size_t)idx;
    float4 a = p[0], bb = p[1];
    uint4 v;
    v.x = pack2(a.x, a.y); v.y = pack2(a.z, a.w);
    v.z = pack2(bb.x, bb.y); v.w = pack2(bb.z, bb.w);
    out[idx] = v;
}

// ---------------------------------------------------------------------------
// prep: all independent front work in ONE launch (3 crops + 3 whh cvts).
// ---------------------------------------------------------------------------
__global__ __launch_bounds__(256) void prep_kernel(
    const float* __restrict__ x1, const float* __restrict__ x2,
    const float* __restrict__ x3, const int* __restrict__ patchs,
    float* __restrict__ local1, float* __restrict__ local2,
    float* __restrict__ local3,
    const float* __restrict__ l1_whh, uint4* __restrict__ whh1b,
    const float* __restrict__ l2_whh, uint4* __restrict__ whh2b,
    const float* __restrict__ l3_whh, uint4* __restrict__ whh3b)
{
    int b = blockIdx.x;
    if (b < 1024) {
        crop_dev<56, 4, 16>(b & 15, b >> 4, x1, patchs, local1, 256, 55, 55, 256, 0);
    } else if (b < 2048) {
        int bb = b - 1024;
        crop_dev<28, 4, 8>(bb & 15, bb >> 4, x2, patchs, local2, 512, 27, 55, 768, 0);
    } else if (b < 4096) {
        int bb = b - 2048;
        crop_dev<14, 2, 8>(bb & 31, bb >> 5, x3, patchs, local3, 1024, 13, 55, 1792, 0);
    } else if (b < 4224) {
        cvt_dev(b - 4096, l1_whh, whh1b, 32768);
    } else if (b < 5376) {
        cvt_dev(b - 4224, l2_whh, whh2b, 294912);
    } else {
        cvt_dev(b - 5376, l3_whh, whh3b, 1605632);
    }
}

// ---------------------------------------------------------------------------
// bf16 MFMA gemm, 64xBN tile (BN in {64,128}). C[m,o]=sum_k X[m,k]W[o,k].
// ---------------------------------------------------------------------------
template<int BN, bool WBF>
__global__ __launch_bounds__(256) void gemm_kernel(
    const float* __restrict__ X, int ldx,
    const void* __restrict__ Wp, int K,
    const float* __restrict__ bias,
    float* __restrict__ out, int ldo,
    int kchunk, int partial)
{
    constexpr int NF = BN / 64;
    __shared__ short Xs[64][72];
    __shared__ short Ws[BN][72];
    int tid = threadIdx.x;
    int lane = tid & 63, wv = tid >> 6;
    int m0 = blockIdx.y * 64;
    int o0 = blockIdx.x * BN;
    int z = blockIdx.z;
    int kbeg = z * kchunk, kend = kbeg + kchunk;

    f32x4 acc[4][NF];
    #pragma unroll
    for (int i = 0; i < 4; ++i)
        #pragma unroll
        for (int j = 0; j < NF; ++j)
            acc[i][j] = (f32x4){0.f, 0.f, 0.f, 0.f};

    for (int kb = kbeg; kb < kend; kb += 64) {
        #pragma unroll
        for (int i = 0; i < 2; ++i) {
            int cch = tid + 256 * i;
            int r = cch >> 3, col = (cch & 7) * 8;
            const float* src = X + (size_t)(m0 + r) * ldx + kb + col;
            float4 a = *reinterpret_cast<const float4*>(src);
            float4 b = *reinterpret_cast<const float4*>(src + 4);
            uint4 v;
            v.x = pack2(a.x, a.y); v.y = pack2(a.z, a.w);
            v.z = pack2(b.x, b.y); v.w = pack2(b.z, b.w);
            *reinterpret_cast<uint4*>(&Xs[r][col]) = v;
        }
        #pragma unroll
        for (int i = 0; i < 2 * NF; ++i) {
            int cch = tid + 256 * i;
            int r = cch >> 3, col = (cch & 7) * 8;
            if constexpr (WBF) {
                const short* srcw = (const short*)Wp + (size_t)(o0 + r) * K + kb + col;
                *reinterpret_cast<uint4*>(&Ws[r][col]) =
                    *reinterpret_cast<const uint4*>(srcw);
            } else {
                const float* srcw = (const float*)Wp + (size_t)(o0 + r) * K + kb + col;
                float4 c = *reinterpret_cast<const float4*>(srcw);
                float4 d = *reinterpret_cast<const float4*>(srcw + 4);
                uint4 w;
                w.x = pack2(c.x, c.y); w.y = pack2(c.z, c.w);
                w.z = pack2(d.x, d.y); w.w = pack2(d.z, d.w);
                *reinterpret_cast<uint4*>(&Ws[r][col]) = w;
            }
        }
        __syncthreads();
        #pragma unroll
        for (int kk = 0; kk < 64; kk += 32) {
            int ro = lane & 15, kof = kk + (lane >> 4) * 8;
            short8 b[NF];
            #pragma unroll
            for (int j = 0; j < NF; ++j)
                b[j] = *reinterpret_cast<const short8*>(
                    &Ws[wv * (BN / 4) + 16 * j + ro][kof]);
            #pragma unroll
            for (int i = 0; i < 4; ++i) {
                short8 a = *reinterpret_cast<const short8*>(&Xs[16 * i + ro][kof]);
                #pragma unroll
                for (int j = 0; j < NF; ++j)
                    acc[i][j] = __builtin_amdgcn_mfma_f32_16x16x32_bf16(
                        a, b[j], acc[i][j], 0, 0, 0);
            }
        }
        __syncthreads();
    }

    float* dst = out;
    if (partial) dst += (size_t)z * (gridDim.y * 64) * ldo;
    int mr = (lane >> 4) * 4;
    #pragma unroll
    for (int j = 0; j < NF; ++j) {
        int o = o0 + wv * (BN / 4) + 16 * j + (lane & 15);
        float bv = (!partial && bias) ? bias[o] : 0.f;
        #pragma unroll
        for (int i = 0; i < 4; ++i) {
            #pragma unroll
            for (int r = 0; r < 4; ++r) {
                int m = m0 + 16 * i + mr + r;
                dst[(size_t)m * ldo + o] = acc[i][j][r] + bv;
            }
        }
    }
}

// ---------------------------------------------------------------------------
// Persistent L1 LSTM: one block per batch row n (64 blocks) — the recurrence
// is independent per batch row, so NO inter-block sync of any kind. h in LDS,
// c in a register (thread j owns unit j). Per step: thread computes gate
// outputs o = 4*tid..4*tid+3 as f32 dots over h_lds with bf16 whh rows
// (L2-resident, 512 KB), exchange via gbuf, cell, write h + dest.
// ---------------------------------------------------------------------------
__global__ __launch_bounds__(256) void lstm_l1_kernel(
    const short* __restrict__ whhb,   // [1024][256] bf16 row-major
    const float* __restrict__ xg,     // [448,1024], row n*7+t (bias included)
    float* __restrict__ local2)       // dest: row (n*7+t)*768, offset 512+j
{
    __shared__ float h_lds[256];
    __shared__ float gbuf[1024];
    int n = blockIdx.x, tid = threadIdx.x;
    float creg = 0.f;

    for (int t = 0; t < PP; ++t) {
        const float* xrow = xg + (size_t)(n * PP + t) * 1024;
        float gi_, gf_, gg_, go_;
        if (t == 0) {
            gi_ = xrow[tid]; gf_ = xrow[256 + tid];
            gg_ = xrow[512 + tid]; go_ = xrow[768 + tid];
        } else {
            float acc[4] = {0.f, 0.f, 0.f, 0.f};
            for (int k8 = 0; k8 < 256; k8 += 8) {
                float hv[8];
                #pragma unroll
                for (int e = 0; e < 8; ++e) hv[e] = h_lds[k8 + e];
                #pragma unroll
                for (int r = 0; r < 4; ++r) {
                    int o = tid * 4 + r;
                    short8 w = *reinterpret_cast<const short8*>(
                        whhb + (size_t)o * 256 + k8);
                    #pragma unroll
                    for (int e = 0; e < 8; ++e)
                        acc[r] = fmaf(bf2f(w[e]), hv[e], acc[r]);
                }
            }
            #pragma unroll
            for (int r = 0; r < 4; ++r) gbuf[tid * 4 + r] = acc[r];
            __syncthreads();
            gi_ = xrow[tid] + gbuf[tid];
            gf_ = xrow[256 + tid] + gbuf[256 + tid];
            gg_ = xrow[512 + tid] + gbuf[512 + tid];
            go_ = xrow[768 + tid] + gbuf[768 + tid];
        }
        float si = 1.f / (1.f + expf(-gi_));
        float sf = 1.f / (1.f + expf(-gf_));
        float so = 1.f / (1.f + expf(-go_));
        creg = sf * creg + si * tanhf(gg_);
        float hn = so * tanhf(creg);
        if (t > 0) __syncthreads();   // ensure all gbuf/h reads done
        h_lds[tid] = hn;
        local2[(size_t)(n * PP + t) * 768 + 512 + tid] = hn;
        __syncthreads();              // h ready for next step
    }
}

// ---------------------------------------------------------------------------
// reduce split-K partials
// ---------------------------------------------------------------------------
__global__ __launch_bounds__(256) void reduce_kernel(
    const float* __restrict__ partial, int S, int M, int O,
    const float* __restrict__ bias, int relu, float* __restrict__ out)
{
    int idx = blockIdx.x * 256 + threadIdx.x;
    int tot = M * O;
    if (idx >= tot) return;
    float v = bias[idx % O];
    for (int s = 0; s < S; ++s) v += partial[(size_t)s * tot + idx];
    if (relu) v = fmaxf(v, 0.f);
    out[idx] = v;
}

// ---------------------------------------------------------------------------
// LSTM cell (L2/L3 path), float4 per thread.
// ---------------------------------------------------------------------------
__global__ __launch_bounds__(256) void lstm_cell_kernel(
    const float* __restrict__ partial, int S,
    const float* __restrict__ xgt, int ldxg,
    float* __restrict__ h, float* __restrict__ c,
    float* __restrict__ dest, int Hd, int ldd, int first)
{
    int idx = blockIdx.x * 256 + threadIdx.x;
    int q = Hd >> 2;
    if (idx >= NB * q) return;
    int n = idx / q, j4 = (idx - n * q) * 4;
    int H4 = 4 * Hd;

    f32x4 g[4];
    #pragma unroll
    for (int gi = 0; gi < 4; ++gi)
        g[gi] = *reinterpret_cast<const f32x4*>(xgt + (size_t)n * ldxg + gi * Hd + j4);
    if (!first) {
        for (int s = 0; s < S; ++s) {
            const float* pr = partial + ((size_t)s * NB + n) * H4;
            #pragma unroll
            for (int gi = 0; gi < 4; ++gi)
                g[gi] += *reinterpret_cast<const f32x4*>(pr + gi * Hd + j4);
        }
    }
    f32x4 cp = (f32x4){0.f, 0.f, 0.f, 0.f};
    if (!first) cp = *reinterpret_cast<const f32x4*>(c + (size_t)n * Hd + j4);

    f32x4 cn, hn;
    #pragma unroll
    for (int k = 0; k < 4; ++k) {
        float si = 1.f / (1.f + expf(-g[0][k]));
        float sf = 1.f / (1.f + expf(-g[1][k]));
        float so = 1.f / (1.f + expf(-g[3][k]));
        float cc = sf * cp[k] + si * tanhf(g[2][k]);
        cn[k] = cc;
        hn[k] = so * tanhf(cc);
    }
    *reinterpret_cast<f32x4*>(c + (size_t)n * Hd + j4) = cn;
    *reinterpret_cast<f32x4*>(h + (size_t)n * Hd + j4) = hn;
    *reinterpret_cast<f32x4*>(dest + (size_t)n * ldd + j4) = hn;
}

// ---------------------------------------------------------------------------
// fused attn logits + softmax + weighted pool
// ---------------------------------------------------------------------------
__global__ __launch_bounds__(256) void attn_fused_kernel(
    const float* __restrict__ h2, const float* __restrict__ aw3,
    const float* __restrict__ ab3, const float* __restrict__ rnn3,
    float* __restrict__ feat)
{
    int n = blockIdx.x;
    int tid = threadIdx.x, lane = tid & 63, wv = tid >> 6;
    __shared__ float logit[PP];
    __shared__ float alpha[PP];
    for (int p = wv; p < PP; p += 4) {
        float s = 0.f;
        for (int k = lane; k < 1792; k += 64)
            s += h2[n * 1792 + k] * aw3[p * 1792 + k];
        #pragma unroll
        for (int off = 32; off; off >>= 1) s += __shfl_down(s, off, 64);
        if (lane == 0) logit[p] = fmaxf(s + ab3[p], 0.f);
    }
    __syncthreads();
    if (tid == 0) {
        float a[PP], mx = -1e30f;
        for (int p = 0; p < PP; ++p) { a[p] = logit[p]; mx = fmaxf(mx, a[p]); }
        float s = 0.f;
        for (int p = 0; p < PP; ++p) { a[p] = expf(a[p] - mx); s += a[p]; }
        for (int p = 0; p < PP; ++p) alpha[p] = a[p] / s;
    }
    __syncthreads();
    for (int j = tid; j < 1792; j += 256) {
        float s = 0.f;
        #pragma unroll
        for (int p = 0; p < PP; ++p)
            s += rnn3[((size_t)n * PP + p) * 1792 + j] * alpha[p];
        feat[(size_t)n * 1792 + j] = s;
    }
}

// ---------------------------------------------------------------------------

extern "C" void kernel_launch(void* const* d_in, const int* in_sizes, int n_in,
                              void* d_out, int out_size, void* d_ws, size_t ws_size,
                              hipStream_t stream) {
    const float* x1 = (const float*)d_in[0];
    const float* x2 = (const float*)d_in[1];
    const float* x3 = (const float*)d_in[2];
    const int* patchs = (const int*)d_in[3];
    const float* l1_wih = (const float*)d_in[4];
    const float* l1_whh = (const float*)d_in[5];
    const float* l1_b   = (const float*)d_in[6];
    const float* l2_wih = (const float*)d_in[7];
    const float* l2_whh = (const float*)d_in[8];
    const float* l2_b   = (const float*)d_in[9];
    const float* l3_wih = (const float*)d_in[10];
    const float* l3_whh = (const float*)d_in[11];
    const float* l3_b   = (const float*)d_in[12];
    const float* aw1 = (const float*)d_in[13];
    const float* ab1 = (const float*)d_in[14];
    const float* aw2 = (const float*)d_in[15];
    const float* ab2 = (const float*)d_in[16];
    const float* aw3 = (const float*)d_in[17];
    const float* ab3 = (const float*)d_in[18];
    const float* fw  = (const float*)d_in[19];
    const float* fb  = (const float*)d_in[20];
    float* out = (float*)d_out;

    float* ws = (float*)d_ws;
    float* local1 = ws;                       // [448,256]
    float* local2 = local1 + 114688;          // [448,768]
    float* local3 = local2 + 344064;          // [448,1792]
    float* rnn3   = local3;                   // alias: local3 dead after xg3
    float* xg     = local3 + 802816;          // [448,7168] max
    float* partial= xg + 3211264;             // up to 14*64*3584 = 3211264 f32
    float* hbuf   = partial + 3211264;        // [64,1792]
    float* cbuf   = hbuf + 114688;            // [64,1792]
    float* h1     = cbuf + 114688;            // [64,3584]
    float* h2     = h1 + 229376;              // [64,1792]
    float* feat   = h2 + 114688;              // [64,1792]
    float* wb     = feat + 114688;            // bf16 weight pool (as f32 units)
    short* whh1b  = (short*)wb;                     // 4*256*256
    short* whh2b  = (short*)(wb + 131072);          // 4*768*768
    short* whh3b  = (short*)(wb + 131072 + 1179648);

    // ---- prep: crops + whh cvts, one launch ----
    prep_kernel<<<11648, 256, 0, stream>>>(
        x1, x2, x3, patchs, local1, local2, local3,
        l1_whh, (uint4*)whh1b, l2_whh, (uint4*)whh2b, l3_whh, (uint4*)whh3b);

    // ---- L1: H=256 — xg gemm + persistent batch-parallel LSTM ----
    {
        int H4 = 1024;
        gemm_kernel<64, false><<<dim3(16, 7, 1), 256, 0, stream>>>(
            local1, 256, l1_wih, 256, l1_b, xg, H4, 256, 0);
        lstm_l1_kernel<<<64, 256, 0, stream>>>(whh1b, xg, local2);
    }
    // ---- L2: H=768 ----
    {
        int H = 768, H4 = 3072;
        gemm_kernel<64, false><<<dim3(48, 7, 1), 256, 0, stream>>>(
            local2, 768, l2_wih, 768, l2_b, xg, H4, 768, 0);
        for (int t = 0; t < PP; ++t) {
            if (t > 0)
                gemm_kernel<64, true><<<dim3(48, 1, 6), 256, 0, stream>>>(
                    hbuf, H, whh2b, H, nullptr, partial, H4, 128, 1);
            lstm_cell_kernel<<<(NB * H / 4 + 255) / 256, 256, 0, stream>>>(
                partial, 6, xg + (size_t)t * H4, PP * H4,
                hbuf, cbuf, local3 + (size_t)t * 1792 + 1024, H, PP * 1792, t == 0);
        }
    }
    // ---- L3: H=1792 ----
    {
        int H = 1792, H4 = 7168;
        gemm_kernel<128, false><<<dim3(56, 7, 1), 256, 0, stream>>>(
            local3, 1792, l3_wih, 1792, l3_b, xg, H4, 1792, 0);
        for (int t = 0; t < PP; ++t) {
            if (t > 0)
                gemm_kernel<128, true><<<dim3(56, 1, 7), 256, 0, stream>>>(
                    hbuf, H, whh3b, H, nullptr, partial, H4, 256, 1);
            lstm_cell_kernel<<<(NB * H / 4 + 255) / 256, 256, 0, stream>>>(
                partial, 7, xg + (size_t)t * H4, PP * H4,
                hbuf, cbuf, rnn3 + (size_t)t * 1792, H, PP * 1792, t == 0);
        }
    }

    // ---- attention MLP ----
    gemm_kernel<64, false><<<dim3(56, 1, 14), 256, 0, stream>>>(
        rnn3, 12544, aw1, 12544, nullptr, partial, 3584, 896, 1);
    reduce_kernel<<<(64 * 3584 + 255) / 256, 256, 0, stream>>>(
        partial, 14, 64, 3584, ab1, 1, h1);
    gemm_kernel<64, false><<<dim3(28, 1, 7), 256, 0, stream>>>(
        h1, 3584, aw2, 3584, nullptr, partial, 1792, 512, 1);
    reduce_kernel<<<(64 * 1792 + 255) / 256, 256, 0, stream>>>(
        partial, 7, 64, 1792, ab2, 1, h2);
    attn_fused_kernel<<<NB, 256, 0, stream>>>(h2, aw3, ab3, rnn3, feat);
    gemm_kernel<64, false><<<dim3(8, 1, 7), 256, 0, stream>>>(
        feat, 1792, fw, 1792, nullptr, partial, 512, 256, 1);
    reduce_kernel<<<(64 * 512 + 255) / 256, 256, 0, stream>>>(
        partial, 7, 64, 512, fb, 0, out);
}

// Round 20
// 605.168 us; speedup vs baseline: 1.0827x; 1.0827x over previous
//
#include <hip/hip_runtime.h>
#include <hip/hip_bf16.h>
#include <math.h>

#define NB 64
#define PP 7

typedef __attribute__((ext_vector_type(8))) short short8;
typedef __attribute__((ext_vector_type(4))) float f32x4;

// round-to-nearest-even bf16 from f32, packed pair -> u32 (lo=a, hi=b)
static __device__ inline unsigned bf16r(float f) {
    unsigned u = __builtin_bit_cast(unsigned, f);
    u += 0x7fffu + ((u >> 16) & 1u);
    return u >> 16;
}
static __device__ inline unsigned pack2(float a, float b) {
    return bf16r(a) | (bf16r(b) << 16);
}

// ---------------------------------------------------------------------------
// crop v6 + unroll 8: masked-fmac direct accumulation (R17-proven structure);
// unroll 8 doubles loads-in-flight per lane (prep is load-concurrency-bound).
// ---------------------------------------------------------------------------
template<int H, int VEC, int GRP>
__device__ inline void crop_dev(
    int bx, int n, const float* __restrict__ x, const int* __restrict__ patchs,
    float* __restrict__ out, int C, int num, int den, int ldo, int col0)
{
    constexpr int USED = H / VEC;
    constexpr int PPWAVE = 64 / GRP;
    int tid = threadIdx.x, lane = tid & 63, wv = tid >> 6;
    int sub = lane / GRP, xl = lane & (GRP - 1);
    bool act = xl < USED;
    int c = bx * (4 * PPWAVE) + wv * PPWAVE + sub;

    int y0s[PP], yds[PP], x0s[PP], x1s[PP], zer[PP];
    float rarea[PP];
    #pragma unroll
    for (int p = 0; p < PP; ++p) {
        int p0 = patchs[(n * PP + p) * 4 + 0];
        int p1 = patchs[(n * PP + p) * 4 + 1];
        int p2 = patchs[(n * PP + p) * 4 + 2];
        int p3 = patchs[(n * PP + p) * 4 + 3];
        int y0 = p0 * num / den, y1 = p1 * num / den;
        int xx0 = p2 * num / den, xx1 = p3 * num / den;
        y0s[p] = y0; yds[p] = y1 - y0;
        x0s[p] = xx0; x1s[p] = xx1;
        rarea[p] = 1.f / (float)((y1 - y0 + 1) * (xx1 - xx0 + 1));
        zer[p] = (p0 | p1 | p2 | p3) == 0;
    }

    const float* pl = x + ((size_t)n * C + c) * (H * H) + (act ? xl * VEC : 0);

    float acc[PP][VEC];
    #pragma unroll
    for (int p = 0; p < PP; ++p)
        #pragma unroll
        for (int e = 0; e < VEC; ++e) acc[p][e] = 0.f;

    #pragma unroll 8
    for (int y = 0; y < H; ++y) {
        float v[VEC];
        if constexpr (VEC == 4) {
            float4 t = *reinterpret_cast<const float4*>(pl + y * H);
            v[0] = t.x; v[1] = t.y; v[2] = t.z; v[3] = t.w;
        } else {
            float2 t = *reinterpret_cast<const float2*>(pl + y * H);
            v[0] = t.x; v[1] = t.y;
        }
        #pragma unroll
        for (int p = 0; p < PP; ++p) {
            float m = ((unsigned)(y - y0s[p]) <= (unsigned)yds[p]) ? 1.f : 0.f;
            #pragma unroll
            for (int e = 0; e < VEC; ++e)
                acc[p][e] = fmaf(m, v[e], acc[p][e]);
        }
    }

    #pragma unroll
    for (int p = 0; p < PP; ++p) {
        float d = 0.f;
        #pragma unroll
        for (int e = 0; e < VEC; ++e) {
            int col = xl * VEC + e;
            if (col >= x0s[p] && col <= x1s[p]) d += acc[p][e];
        }
        #pragma unroll
        for (int off = GRP / 2; off >= 1; off >>= 1)
            d += __shfl_xor(d, off, 64);
        if (act && xl == 0)
            out[(size_t)(n * PP + p) * ldo + col0 + c] = zer[p] ? 0.f : d * rarea[p];
    }
}

// f32 -> bf16 cvt device fn, 8 elems/thread
__device__ inline void cvt_dev(
    int b, const float* __restrict__ in, uint4* __restrict__ out, int n8)
{
    int idx = b * 256 + threadIdx.x;
    if (idx >= n8) return;
    const float4* p = reinterpret_cast<const float4*>(in) + 2 * (size_t)idx;
    float4 a = p[0], bb = p[1];
    uint4 v;
    v.x = pack2(a.x, a.y); v.y = pack2(a.z, a.w);
    v.z = pack2(bb.x, bb.y); v.w = pack2(bb.z, bb.w);
    out[idx] = v;
}

// ---------------------------------------------------------------------------
// prep: all independent front work in ONE launch (3 crops + 3 whh cvts).
// ---------------------------------------------------------------------------
__global__ __launch_bounds__(256) void prep_kernel(
    const float* __restrict__ x1, const float* __restrict__ x2,
    const float* __restrict__ x3, const int* __restrict__ patchs,
    float* __restrict__ local1, float* __restrict__ local2,
    float* __restrict__ local3,
    const float* __restrict__ l1_whh, uint4* __restrict__ whh1b,
    const float* __restrict__ l2_whh, uint4* __restrict__ whh2b,
    const float* __restrict__ l3_whh, uint4* __restrict__ whh3b)
{
    int b = blockIdx.x;
    if (b < 1024) {
        crop_dev<56, 4, 16>(b & 15, b >> 4, x1, patchs, local1, 256, 55, 55, 256, 0);
    } else if (b < 2048) {
        int bb = b - 1024;
        crop_dev<28, 4, 8>(bb & 15, bb >> 4, x2, patchs, local2, 512, 27, 55, 768, 0);
    } else if (b < 4096) {
        int bb = b - 2048;
        crop_dev<14, 2, 8>(bb & 31, bb >> 5, x3, patchs, local3, 1024, 13, 55, 1792, 0);
    } else if (b < 4224) {
        cvt_dev(b - 4096, l1_whh, whh1b, 32768);
    } else if (b < 5376) {
        cvt_dev(b - 4224, l2_whh, whh2b, 294912);
    } else {
        cvt_dev(b - 5376, l3_whh, whh3b, 1605632);
    }
}

// ---------------------------------------------------------------------------
// bf16 MFMA gemm, 64xBN tile (BN in {64,128}). C[m,o]=sum_k X[m,k]W[o,k].
// ---------------------------------------------------------------------------
template<int BN, bool WBF>
__global__ __launch_bounds__(256) void gemm_kernel(
    const float* __restrict__ X, int ldx,
    const void* __restrict__ Wp, int K,
    const float* __restrict__ bias,
    float* __restrict__ out, int ldo,
    int kchunk, int partial)
{
    constexpr int NF = BN / 64;
    __shared__ short Xs[64][72];
    __shared__ short Ws[BN][72];
    int tid = threadIdx.x;
    int lane = tid & 63, wv = tid >> 6;
    int m0 = blockIdx.y * 64;
    int o0 = blockIdx.x * BN;
    int z = blockIdx.z;
    int kbeg = z * kchunk, kend = kbeg + kchunk;

    f32x4 acc[4][NF];
    #pragma unroll
    for (int i = 0; i < 4; ++i)
        #pragma unroll
        for (int j = 0; j < NF; ++j)
            acc[i][j] = (f32x4){0.f, 0.f, 0.f, 0.f};

    for (int kb = kbeg; kb < kend; kb += 64) {
        #pragma unroll
        for (int i = 0; i < 2; ++i) {
            int cch = tid + 256 * i;
            int r = cch >> 3, col = (cch & 7) * 8;
            const float* src = X + (size_t)(m0 + r) * ldx + kb + col;
            float4 a = *reinterpret_cast<const float4*>(src);
            float4 b = *reinterpret_cast<const float4*>(src + 4);
            uint4 v;
            v.x = pack2(a.x, a.y); v.y = pack2(a.z, a.w);
            v.z = pack2(b.x, b.y); v.w = pack2(b.z, b.w);
            *reinterpret_cast<uint4*>(&Xs[r][col]) = v;
        }
        #pragma unroll
        for (int i = 0; i < 2 * NF; ++i) {
            int cch = tid + 256 * i;
            int r = cch >> 3, col = (cch & 7) * 8;
            if constexpr (WBF) {
                const short* srcw = (const short*)Wp + (size_t)(o0 + r) * K + kb + col;
                *reinterpret_cast<uint4*>(&Ws[r][col]) =
                    *reinterpret_cast<const uint4*>(srcw);
            } else {
                const float* srcw = (const float*)Wp + (size_t)(o0 + r) * K + kb + col;
                float4 c = *reinterpret_cast<const float4*>(srcw);
                float4 d = *reinterpret_cast<const float4*>(srcw + 4);
                uint4 w;
                w.x = pack2(c.x, c.y); w.y = pack2(c.z, c.w);
                w.z = pack2(d.x, d.y); w.w = pack2(d.z, d.w);
                *reinterpret_cast<uint4*>(&Ws[r][col]) = w;
            }
        }
        __syncthreads();
        #pragma unroll
        for (int kk = 0; kk < 64; kk += 32) {
            int ro = lane & 15, kof = kk + (lane >> 4) * 8;
            short8 b[NF];
            #pragma unroll
            for (int j = 0; j < NF; ++j)
                b[j] = *reinterpret_cast<const short8*>(
                    &Ws[wv * (BN / 4) + 16 * j + ro][kof]);
            #pragma unroll
            for (int i = 0; i < 4; ++i) {
                short8 a = *reinterpret_cast<const short8*>(&Xs[16 * i + ro][kof]);
                #pragma unroll
                for (int j = 0; j < NF; ++j)
                    acc[i][j] = __builtin_amdgcn_mfma_f32_16x16x32_bf16(
                        a, b[j], acc[i][j], 0, 0, 0);
            }
        }
        __syncthreads();
    }

    float* dst = out;
    if (partial) dst += (size_t)z * (gridDim.y * 64) * ldo;
    int mr = (lane >> 4) * 4;
    #pragma unroll
    for (int j = 0; j < NF; ++j) {
        int o = o0 + wv * (BN / 4) + 16 * j + (lane & 15);
        float bv = (!partial && bias) ? bias[o] : 0.f;
        #pragma unroll
        for (int i = 0; i < 4; ++i) {
            #pragma unroll
            for (int r = 0; r < 4; ++r) {
                int m = m0 + 16 * i + mr + r;
                dst[(size_t)m * ldo + o] = acc[i][j][r] + bv;
            }
        }
    }
}

// ---------------------------------------------------------------------------
// reduce split-K partials: out[m*O+o] = act(sum_s partial[s][m][o] + bias[o])
// ---------------------------------------------------------------------------
__global__ __launch_bounds__(256) void reduce_kernel(
    const float* __restrict__ partial, int S, int M, int O,
    const float* __restrict__ bias, int relu, float* __restrict__ out)
{
    int idx = blockIdx.x * 256 + threadIdx.x;
    int tot = M * O;
    if (idx >= tot) return;
    float v = bias[idx % O];
    for (int s = 0; s < S; ++s) v += partial[(size_t)s * tot + idx];
    if (relu) v = fmaxf(v, 0.f);
    out[idx] = v;
}

// ---------------------------------------------------------------------------
// LSTM cell, float4 per thread. gates = xgt + sum_s partial (unless first).
// ---------------------------------------------------------------------------
__global__ __launch_bounds__(256) void lstm_cell_kernel(
    const float* __restrict__ partial, int S,
    const float* __restrict__ xgt, int ldxg,
    float* __restrict__ h, float* __restrict__ c,
    float* __restrict__ dest, int Hd, int ldd, int first)
{
    int idx = blockIdx.x * 256 + threadIdx.x;
    int q = Hd >> 2;
    if (idx >= NB * q) return;
    int n = idx / q, j4 = (idx - n * q) * 4;
    int H4 = 4 * Hd;

    f32x4 g[4];
    #pragma unroll
    for (int gi = 0; gi < 4; ++gi)
        g[gi] = *reinterpret_cast<const f32x4*>(xgt + (size_t)n * ldxg + gi * Hd + j4);
    if (!first) {
        for (int s = 0; s < S; ++s) {
            const float* pr = partial + ((size_t)s * NB + n) * H4;
            #pragma unroll
            for (int gi = 0; gi < 4; ++gi)
                g[gi] += *reinterpret_cast<const f32x4*>(pr + gi * Hd + j4);
        }
    }
    f32x4 cp = (f32x4){0.f, 0.f, 0.f, 0.f};
    if (!first) cp = *reinterpret_cast<const f32x4*>(c + (size_t)n * Hd + j4);

    f32x4 cn, hn;
    #pragma unroll
    for (int k = 0; k < 4; ++k) {
        float si = 1.f / (1.f + expf(-g[0][k]));
        float sf = 1.f / (1.f + expf(-g[1][k]));
        float so = 1.f / (1.f + expf(-g[3][k]));
        float cc = sf * cp[k] + si * tanhf(g[2][k]);
        cn[k] = cc;
        hn[k] = so * tanhf(cc);
    }
    *reinterpret_cast<f32x4*>(c + (size_t)n * Hd + j4) = cn;
    *reinterpret_cast<f32x4*>(h + (size_t)n * Hd + j4) = hn;
    *reinterpret_cast<f32x4*>(dest + (size_t)n * ldd + j4) = hn;
}

// ---------------------------------------------------------------------------
// fused attn logits + softmax + weighted pool
// ---------------------------------------------------------------------------
__global__ __launch_bounds__(256) void attn_fused_kernel(
    const float* __restrict__ h2, const float* __restrict__ aw3,
    const float* __restrict__ ab3, const float* __restrict__ rnn3,
    float* __restrict__ feat)
{
    int n = blockIdx.x;
    int tid = threadIdx.x, lane = tid & 63, wv = tid >> 6;
    __shared__ float logit[PP];
    __shared__ float alpha[PP];
    for (int p = wv; p < PP; p += 4) {
        float s = 0.f;
        for (int k = lane; k < 1792; k += 64)
            s += h2[n * 1792 + k] * aw3[p * 1792 + k];
        #pragma unroll
        for (int off = 32; off; off >>= 1) s += __shfl_down(s, off, 64);
        if (lane == 0) logit[p] = fmaxf(s + ab3[p], 0.f);
    }
    __syncthreads();
    if (tid == 0) {
        float a[PP], mx = -1e30f;
        for (int p = 0; p < PP; ++p) { a[p] = logit[p]; mx = fmaxf(mx, a[p]); }
        float s = 0.f;
        for (int p = 0; p < PP; ++p) { a[p] = expf(a[p] - mx); s += a[p]; }
        for (int p = 0; p < PP; ++p) alpha[p] = a[p] / s;
    }
    __syncthreads();
    for (int j = tid; j < 1792; j += 256) {
        float s = 0.f;
        #pragma unroll
        for (int p = 0; p < PP; ++p)
            s += rnn3[((size_t)n * PP + p) * 1792 + j] * alpha[p];
        feat[(size_t)n * 1792 + j] = s;
    }
}

// ---------------------------------------------------------------------------

extern "C" void kernel_launch(void* const* d_in, const int* in_sizes, int n_in,
                              void* d_out, int out_size, void* d_ws, size_t ws_size,
                              hipStream_t stream) {
    const float* x1 = (const float*)d_in[0];
    const float* x2 = (const float*)d_in[1];
    const float* x3 = (const float*)d_in[2];
    const int* patchs = (const int*)d_in[3];
    const float* l1_wih = (const float*)d_in[4];
    const float* l1_whh = (const float*)d_in[5];
    const float* l1_b   = (const float*)d_in[6];
    const float* l2_wih = (const float*)d_in[7];
    const float* l2_whh = (const float*)d_in[8];
    const float* l2_b   = (const float*)d_in[9];
    const float* l3_wih = (const float*)d_in[10];
    const float* l3_whh = (const float*)d_in[11];
    const float* l3_b   = (const float*)d_in[12];
    const float* aw1 = (const float*)d_in[13];
    const float* ab1 = (const float*)d_in[14];
    const float* aw2 = (const float*)d_in[15];
    const float* ab2 = (const float*)d_in[16];
    const float* aw3 = (const float*)d_in[17];
    const float* ab3 = (const float*)d_in[18];
    const float* fw  = (const float*)d_in[19];
    const float* fb  = (const float*)d_in[20];
    float* out = (float*)d_out;

    float* ws = (float*)d_ws;
    float* local1 = ws;                       // [448,256]
    float* local2 = local1 + 114688;          // [448,768]
    float* local3 = local2 + 344064;          // [448,1792]
    float* rnn3   = local3;                   // alias: local3 dead after xg3
    float* xg     = local3 + 802816;          // [448,7168] max
    float* partial= xg + 3211264;             // up to 14*64*3584 = 3211264 f32
    float* hbuf   = partial + 3211264;        // [64,1792]
    float* cbuf   = hbuf + 114688;            // [64,1792]
    float* h1     = cbuf + 114688;            // [64,3584]
    float* h2     = h1 + 229376;              // [64,1792]
    float* feat   = h2 + 114688;              // [64,1792]
    float* wb     = feat + 114688;            // bf16 weight pool (as f32 units)
    short* whh1b  = (short*)wb;                     // 4*256*256
    short* whh2b  = (short*)(wb + 131072);          // 4*768*768
    short* whh3b  = (short*)(wb + 131072 + 1179648);

    // ---- prep: crops + whh cvts, one launch ----
    prep_kernel<<<11648, 256, 0, stream>>>(
        x1, x2, x3, patchs, local1, local2, local3,
        l1_whh, (uint4*)whh1b, l2_whh, (uint4*)whh2b, l3_whh, (uint4*)whh3b);

    // ---- L1: H=256 ----
    {
        int H = 256, H4 = 1024;
        gemm_kernel<64, false><<<dim3(16, 7, 1), 256, 0, stream>>>(
            local1, 256, l1_wih, 256, l1_b, xg, H4, 256, 0);
        for (int t = 0; t < PP; ++t) {
            if (t > 0)
                gemm_kernel<64, true><<<dim3(16, 1, 4), 256, 0, stream>>>(
                    hbuf, H, whh1b, H, nullptr, partial, H4, 64, 1);
            lstm_cell_kernel<<<(NB * H / 4 + 255) / 256, 256, 0, stream>>>(
                partial, 4, xg + (size_t)t * H4, PP * H4,
                hbuf, cbuf, local2 + (size_t)t * 768 + 512, H, PP * 768, t == 0);
        }
    }
    // ---- L2: H=768 ----
    {
        int H = 768, H4 = 3072;
        gemm_kernel<64, false><<<dim3(48, 7, 1), 256, 0, stream>>>(
            local2, 768, l2_wih, 768, l2_b, xg, H4, 768, 0);
        for (int t = 0; t < PP; ++t) {
            if (t > 0)
                gemm_kernel<64, true><<<dim3(48, 1, 6), 256, 0, stream>>>(
                    hbuf, H, whh2b, H, nullptr, partial, H4, 128, 1);
            lstm_cell_kernel<<<(NB * H / 4 + 255) / 256, 256, 0, stream>>>(
                partial, 6, xg + (size_t)t * H4, PP * H4,
                hbuf, cbuf, local3 + (size_t)t * 1792 + 1024, H, PP * 1792, t == 0);
        }
    }
    // ---- L3: H=1792 ----
    {
        int H = 1792, H4 = 7168;
        gemm_kernel<128, false><<<dim3(56, 7, 1), 256, 0, stream>>>(
            local3, 1792, l3_wih, 1792, l3_b, xg, H4, 1792, 0);
        for (int t = 0; t < PP; ++t) {
            if (t > 0)
                gemm_kernel<128, true><<<dim3(56, 1, 7), 256, 0, stream>>>(
                    hbuf, H, whh3b, H, nullptr, partial, H4, 256, 1);
            lstm_cell_kernel<<<(NB * H / 4 + 255) / 256, 256, 0, stream>>>(
                partial, 7, xg + (size_t)t * H4, PP * H4,
                hbuf, cbuf, rnn3 + (size_t)t * 1792, H, PP * 1792, t == 0);
        }
    }

    // ---- attention MLP ----
    // aw1: [64,12544] x [3584,12544]^T, split-K 14 -> 784 blocks
    gemm_kernel<64, false><<<dim3(56, 1, 14), 256, 0, stream>>>(
        rnn3, 12544, aw1, 12544, nullptr, partial, 3584, 896, 1);
    reduce_kernel<<<(64 * 3584 + 255) / 256, 256, 0, stream>>>(
        partial, 14, 64, 3584, ab1, 1, h1);
    // aw2: [64,3584] x [1792,3584]^T, split-K 7 -> 196 blocks
    gemm_kernel<64, false><<<dim3(28, 1, 7), 256, 0, stream>>>(
        h1, 3584, aw2, 3584, nullptr, partial, 1792, 512, 1);
    reduce_kernel<<<(64 * 1792 + 255) / 256, 256, 0, stream>>>(
        partial, 7, 64, 1792, ab2, 1, h2);
    attn_fused_kernel<<<NB, 256, 0, stream>>>(h2, aw3, ab3, rnn3, feat);
    gemm_kernel<64, false><<<dim3(8, 1, 7), 256, 0, stream>>>(
        feat, 1792, fw, 1792, nullptr, partial, 512, 256, 1);
    reduce_kernel<<<(64 * 512 + 255) / 256, 256, 0, stream>>>(
        partial, 7, 64, 512, fb, 0, out);
}